// Round 17
// baseline (302.925 us; speedup 1.0000x reference)
//
#include <hip/hip_runtime.h>
#include <hip/hip_bf16.h>
#include <math.h>

// Problem constants (fixed by the reference):
constexpr int Cc = 512;   // channels
constexpr int Hh = 8;     // heads
constexpr int Dd = 64;    // head dim
constexpr int Nn = 2048;  // kv length
constexpr int Bb = 8;     // batch
constexpr int GK = 512;   // K dim of every GEMM here

typedef __attribute__((ext_vector_type(8))) short short8;
typedef __attribute__((ext_vector_type(4))) float f32x4;
typedef __attribute__((ext_vector_type(4))) unsigned int u32x4;
typedef __attribute__((ext_vector_type(2))) unsigned int u32x2;

// scale * log2(e) folded into Q at projection time
#define C2SCALE 0.1803368801f

static __device__ __forceinline__ ushort f2bf(float v) {
  __hip_bfloat16 h = __float2bfloat16(v);
  return *reinterpret_cast<ushort*>(&h);
}
static __device__ __forceinline__ float bf2f(ushort u) {
  __hip_bfloat16 h = *reinterpret_cast<__hip_bfloat16*>(&u);
  return __bfloat162float(h);
}
// pack two f32 -> u32 of two bf16 (f0 low, f1 high), RNE via f2bf
static __device__ __forceinline__ unsigned int pk2(float f0, float f1) {
  return (unsigned int)f2bf(f0) | ((unsigned int)f2bf(f1) << 16);
}

// ---------------------------------------------------------------------------
// MFMA GEMM with fused dtype handling (proven): C = A B^T (+bias).
// Used for Q (MODE 2, 1-term) and proj (MODE 0, 3-term).
// ---------------------------------------------------------------------------
template <int MODE, int TERMS, bool AF32, bool BF32>
__global__ __launch_bounds__(256) void mfma_nt2_kernel(
    const void* __restrict__ A0p, const void* __restrict__ A1p,
    const void* __restrict__ B0p, const void* __restrict__ B1p,
    const float* __restrict__ bias, float* __restrict__ Cf,
    ushort* __restrict__ Chi, int Nc)
{
  __shared__ ushort lAh[128 * 32];
  __shared__ ushort lBh[128 * 32];
  __shared__ ushort lAl[TERMS == 3 ? 128 * 32 : 1];
  __shared__ ushort lBl[TERMS == 3 ? 128 * 32 : 1];

  const int tid = threadIdx.x;
  const int w = tid >> 6, lane = tid & 63;
  const int c = lane & 15, g = lane >> 4;
  const int wr = (w >> 1) * 64, wc = (w & 1) * 64;
  const int m0 = blockIdx.y * 128, n0 = blockIdx.x * 128;
  const int sr = tid >> 2;          // staging row 0..63
  const int sk = (tid & 3) * 8;     // staging k-offset (elements)

  short8 rAh[2], rAl[2], rBh[2], rBl[2];

  auto ldf32 = [&](const float* F, size_t idx, short8& h, short8& l) {
    const float4 f0 = *(const float4*)(F + idx);
    const float4 f1 = *(const float4*)(F + idx + 4);
    const float vv[8] = {f0.x, f0.y, f0.z, f0.w, f1.x, f1.y, f1.z, f1.w};
#pragma unroll
    for (int j = 0; j < 8; ++j) {
      const ushort hb = f2bf(vv[j]);
      ((ushort*)&h)[j] = hb;
      if (TERMS == 3) ((ushort*)&l)[j] = f2bf(vv[j] - bf2f(hb));
    }
  };

  auto loadA = [&](int k0) {
#pragma unroll
    for (int hf = 0; hf < 2; ++hf) {
      const size_t idx = (size_t)(m0 + sr + hf * 64) * GK + k0 + sk;
      if (AF32) {
        ldf32((const float*)A0p, idx, rAh[hf], rAl[hf]);
      } else {
        rAh[hf] = *(const short8*)((const ushort*)A0p + idx);
        if (TERMS == 3) rAl[hf] = *(const short8*)((const ushort*)A1p + idx);
      }
    }
  };
  auto loadB = [&](int k0) {
#pragma unroll
    for (int hf = 0; hf < 2; ++hf) {
      const size_t idx = (size_t)(n0 + sr + hf * 64) * GK + k0 + sk;
      if (BF32) {
        ldf32((const float*)B0p, idx, rBh[hf], rBl[hf]);
      } else {
        rBh[hf] = *(const short8*)((const ushort*)B0p + idx);
        if (TERMS == 3) rBl[hf] = *(const short8*)((const ushort*)B1p + idx);
      }
    }
  };

  f32x4 acc[4][4] = {};
  loadA(0);
  loadB(0);

  for (int k0 = 0; k0 < GK; k0 += 32) {
    __syncthreads();
    *(short8*)&lAh[sr * 32 + sk]        = rAh[0];
    *(short8*)&lAh[(sr + 64) * 32 + sk] = rAh[1];
    *(short8*)&lBh[sr * 32 + sk]        = rBh[0];
    *(short8*)&lBh[(sr + 64) * 32 + sk] = rBh[1];
    if (TERMS == 3) {
      *(short8*)&lAl[sr * 32 + sk]        = rAl[0];
      *(short8*)&lAl[(sr + 64) * 32 + sk] = rAl[1];
      *(short8*)&lBl[sr * 32 + sk]        = rBl[0];
      *(short8*)&lBl[(sr + 64) * 32 + sk] = rBl[1];
    }
    __syncthreads();
    if (k0 + 32 < GK) { loadA(k0 + 32); loadB(k0 + 32); }  // T14 issue-early

    short8 ah[4], al[4], bh[4], bl[4];
#pragma unroll
    for (int i = 0; i < 4; ++i) {
      const int ar = (wr + i * 16 + c) * 32 + g * 8;
      const int br = (wc + i * 16 + c) * 32 + g * 8;
      ah[i] = *(const short8*)&lAh[ar];
      bh[i] = *(const short8*)&lBh[br];
      if (TERMS == 3) {
        al[i] = *(const short8*)&lAl[ar];
        bl[i] = *(const short8*)&lBl[br];
      }
    }
#pragma unroll
    for (int mi = 0; mi < 4; ++mi)
#pragma unroll
      for (int nj = 0; nj < 4; ++nj) {
        if (TERMS == 3) {
          acc[mi][nj] = __builtin_amdgcn_mfma_f32_16x16x32_bf16(ah[mi], bl[nj], acc[mi][nj], 0,0,0);
          acc[mi][nj] = __builtin_amdgcn_mfma_f32_16x16x32_bf16(al[mi], bh[nj], acc[mi][nj], 0,0,0);
        }
        acc[mi][nj] = __builtin_amdgcn_mfma_f32_16x16x32_bf16(ah[mi], bh[nj], acc[mi][nj], 0,0,0);
      }
  }

#pragma unroll
  for (int mi = 0; mi < 4; ++mi) {
#pragma unroll
    for (int r = 0; r < 4; ++r) {
      const size_t rb = (size_t)(m0 + wr + mi * 16 + g * 4 + r) * Nc;
#pragma unroll
      for (int nj = 0; nj < 4; ++nj) {
        const int col = n0 + wc + nj * 16 + c;
        const float v = acc[mi][nj][r];
        if (MODE == 0) {
          Cf[rb + col] = v + bias[col];
        } else if (MODE == 1) {
          Chi[rb + col] = f2bf(v);
        } else {
          Chi[rb + col] = f2bf(v * C2SCALE);   // Q pre-scaled for exp2 domain
        }
      }
    }
  }
}

// ---------------------------------------------------------------------------
// Fused K+V projection GEMM: stages each x-tile ONCE, computes
//   k = x @ Wk^T   -> k_bf (BN, C) bf16, normal epilogue
//   v = x @ Wv^T   -> v_t  (C, BN) bf16, TRANSPOSED epilogue through LDS
// (reuses the dead staging LDS; scalar transpose writes are 2-way-conflict
//  free at stride 272B; reads + global writes fully coalesced b128).
// Same k-summation order as the separate kernels -> identical rounding.
// ---------------------------------------------------------------------------
__global__ __launch_bounds__(256, 2) void mfma_kv_fused_kernel(
    const float* __restrict__ x, const float* __restrict__ Wkv,
    ushort* __restrict__ kbf, ushort* __restrict__ vtb, int BN)
{
  __shared__ ushort smem[128 * 136];       // 34.8 KB
  ushort* lA   = smem;                     // 128*32 (staging phase)
  ushort* lBk  = smem + 128 * 32;
  ushort* lBv  = smem + 2 * 128 * 32;
  ushort* tbuf = smem;                     // 128*136 (epilogue phase)

  const int tid = threadIdx.x;
  const int w = tid >> 6, lane = tid & 63;
  const int c = lane & 15, g = lane >> 4;
  const int wr = (w >> 1) * 64, wc = (w & 1) * 64;
  const int n0 = blockIdx.x * 128, m0 = blockIdx.y * 128;
  const int sr = tid >> 2, sk = (tid & 3) * 8;

  auto cvt8 = [&](const float* F, size_t idx) -> short8 {
    const float4 f0 = *(const float4*)(F + idx);
    const float4 f1 = *(const float4*)(F + idx + 4);
    const float vv[8] = {f0.x, f0.y, f0.z, f0.w, f1.x, f1.y, f1.z, f1.w};
    short8 h;
#pragma unroll
    for (int j = 0; j < 8; ++j) ((ushort*)&h)[j] = f2bf(vv[j]);
    return h;
  };

  short8 rA[2], rBk[2], rBv[2];
  auto loadAll = [&](int k0) {
#pragma unroll
    for (int hf = 0; hf < 2; ++hf) {
      rA[hf]  = cvt8(x,   (size_t)(m0 + sr + hf * 64) * GK + k0 + sk);
      rBk[hf] = cvt8(Wkv, (size_t)(n0 + sr + hf * 64) * GK + k0 + sk);
      rBv[hf] = cvt8(Wkv, (size_t)(512 + n0 + sr + hf * 64) * GK + k0 + sk);
    }
  };

  f32x4 ak[4][4] = {};
  f32x4 av[4][4] = {};
  loadAll(0);

  for (int k0 = 0; k0 < GK; k0 += 32) {
    __syncthreads();
    *(short8*)&lA[sr * 32 + sk]         = rA[0];
    *(short8*)&lA[(sr + 64) * 32 + sk]  = rA[1];
    *(short8*)&lBk[sr * 32 + sk]        = rBk[0];
    *(short8*)&lBk[(sr + 64) * 32 + sk] = rBk[1];
    *(short8*)&lBv[sr * 32 + sk]        = rBv[0];
    *(short8*)&lBv[(sr + 64) * 32 + sk] = rBv[1];
    __syncthreads();
    if (k0 + 32 < GK) loadAll(k0 + 32);   // T14 issue-early

    short8 a[4], bk[4], bv[4];
#pragma unroll
    for (int i = 0; i < 4; ++i) {
      const int ar = (wr + i * 16 + c) * 32 + g * 8;
      const int br = (wc + i * 16 + c) * 32 + g * 8;
      a[i]  = *(const short8*)&lA[ar];
      bk[i] = *(const short8*)&lBk[br];
      bv[i] = *(const short8*)&lBv[br];
    }
#pragma unroll
    for (int mi = 0; mi < 4; ++mi)
#pragma unroll
      for (int nj = 0; nj < 4; ++nj) {
        ak[mi][nj] = __builtin_amdgcn_mfma_f32_16x16x32_bf16(a[mi], bk[nj], ak[mi][nj], 0,0,0);
        av[mi][nj] = __builtin_amdgcn_mfma_f32_16x16x32_bf16(a[mi], bv[nj], av[mi][nj], 0,0,0);
      }
  }

  // ---- K epilogue: normal bf16 store ----
#pragma unroll
  for (int mi = 0; mi < 4; ++mi)
#pragma unroll
    for (int r = 0; r < 4; ++r) {
      const size_t rb = (size_t)(m0 + wr + mi * 16 + g * 4 + r) * Cc;
#pragma unroll
      for (int nj = 0; nj < 4; ++nj)
        kbf[rb + n0 + wc + nj * 16 + c] = f2bf(ak[mi][nj][r]);
    }

  // ---- V epilogue: transpose through LDS, coalesced v_t store ----
  __syncthreads();   // staging LDS dead (all frags consumed into regs)
#pragma unroll
  for (int mi = 0; mi < 4; ++mi)
#pragma unroll
    for (int r = 0; r < 4; ++r) {
      const int tl = wr + mi * 16 + g * 4 + r;   // token local
#pragma unroll
      for (int nj = 0; nj < 4; ++nj) {
        const int dl = wc + nj * 16 + c;         // d local
        tbuf[dl * 136 + tl] = f2bf(av[mi][nj][r]);
      }
    }
  __syncthreads();
#pragma unroll
  for (int it = 0; it < 8; ++it) {
    const int idx = tid + it * 256;
    const int row = idx >> 4;            // d local 0..127
    const int c8 = (idx & 15) * 8;       // token chunk
    *(short8*)&vtb[(size_t)(n0 + row) * BN + m0 + c8] =
        *(const short8*)&tbuf[row * 136 + c8];
  }
}

// ---------------------------------------------------------------------------
// Swapped-operand MFMA flash attention (R16 structure) + T14 issue-early
// staging: next chunk's global loads land in registers during compute; the
// LDS write happens at the top of the next chunk. Bit-identical data.
// ---------------------------------------------------------------------------
__global__ __launch_bounds__(256, 4) void attn_mfma13_kernel(
    const ushort* __restrict__ qhi,  // (TQ, C) bf16, pre-scaled by C2SCALE
    const ushort* __restrict__ kbf,  // (B*N, C) bf16
    const ushort* __restrict__ vtb,  // (C, B*N) bf16  (V^T)
    ushort* __restrict__ ohi,        // (TQ, C) bf16 hi
    ushort* __restrict__ olo)        // (TQ, C) bf16 lo
{
  // Q_LENGTHS = 1024 + 128*b ; cumulative offsets:
  constexpr int QOFF[8] = {0, 1024, 2176, 3456, 4864, 6400, 8064, 9856};

  const int lin = blockIdx.x;
  const int b  = lin & 7;            // lin%8=b -> batch pinned per XCD
  const int h  = (lin >> 3) & 7;
  const int qt = lin >> 6;

  const int Lb  = 1024 + 128 * b;
  const int off = QOFF[b];
  if (qt * 128 >= Lb) return;        // uniform; lengths are %128==0

  constexpr int KP = 72;             // K row stride (bf16)
  constexpr int VP = 136;            // V row stride (bf16)
  constexpr int NC = Nn / 128;       // 16 chunks of 128 keys
  __shared__ ushort Ks[128 * KP];    // [key][d]
  __shared__ ushort Vs[64 * VP];     // [d][sigma(key) within 128]

  const int tid = threadIdx.x;
  const int lane = tid & 63;
  const int w = tid >> 6;            // wave 0..3 -> q-rows [w*32, w*32+32)
  const int c = lane & 15;           // q (B-col) / key-row (A) / d-row (PV A)
  const int g = (lane >> 4) & 3;     // k-chunk selector

  // Q fragments for two 16-row sub-tiles t: rows w*32 + t*16 + c
  short8 qf[2][2];
  int qrow[2];
#pragma unroll
  for (int t = 0; t < 2; ++t) {
    qrow[t] = off + qt * 128 + w * 32 + t * 16 + c;
    const size_t base = (size_t)qrow[t] * Cc + h * Dd + g * 8;
    qf[t][0] = *(const short8*)(qhi + base);
    qf[t][1] = *(const short8*)(qhi + base + 32);
  }

  float l_part[2] = {0.f, 0.f};
  f32x4 accO4[2][4] = {};

  const size_t kbase = (size_t)b * Nn * Cc + h * Dd;
  const size_t vbase = (size_t)h * Dd * (Bb * Nn) + (size_t)b * Nn;

  short8 rk[4], rv[4];
  auto loadK = [&](int ch) {
#pragma unroll
    for (int it = 0; it < 4; ++it) {
      const int i = tid + it * 256;
      const int row = i >> 3, c8 = (i & 7) * 8;
      rk[it] = *(const short8*)&kbf[kbase + (size_t)(ch * 128 + row) * Cc + c8];
    }
  };
  auto loadV = [&](int ch) {     // sigma^-1 applied on global fetch (R15)
#pragma unroll
    for (int it = 0; it < 4; ++it) {
      const int i = tid + it * 256;
      const int row = i >> 4, c8 = (i & 15) * 8;
      const int kb1 = (c8 & ~31) | (((c8 >> 3) & 3) << 2);
      const size_t gb = vbase + (size_t)row * (Bb * Nn) + ch * 128;
      const u32x2 vlo = *(const u32x2*)&vtb[gb + kb1];
      const u32x2 vhi = *(const u32x2*)&vtb[gb + kb1 + 16];
      u32x4 vv;
      vv[0] = vlo[0]; vv[1] = vlo[1];
      vv[2] = vhi[0]; vv[3] = vhi[1];
      rv[it] = __builtin_bit_cast(short8, vv);
    }
  };

  loadK(0);
  loadV(0);

  for (int ch = 0; ch < NC; ++ch) {
    __syncthreads();   // previous chunk's LDS reads complete
#pragma unroll
    for (int it = 0; it < 4; ++it) {
      const int i = tid + it * 256;
      *(short8*)&Ks[(i >> 3) * KP + (i & 7) * 8] = rk[it];
    }
#pragma unroll
    for (int it = 0; it < 4; ++it) {
      const int i = tid + it * 256;
      *(short8*)&Vs[(i >> 4) * VP + (i & 15) * 8] = rv[it];
    }
    __syncthreads();
    if (ch + 1 < NC) { loadK(ch + 1); loadV(ch + 1); }  // in flight in compute

#pragma unroll
    for (int st = 0; st < 2; ++st) {
      // ---- S^T = K Q^T : one kf read feeds both q-sub-tiles ----
      f32x4 accT4[2][4] = {};
      __builtin_amdgcn_s_setprio(1);
#pragma unroll
      for (int ks2 = 0; ks2 < 2; ++ks2) {
#pragma unroll
        for (int kb = 0; kb < 4; ++kb) {
          const short8 kf = *(const short8*)
              &Ks[(st * 64 + kb * 16 + c) * KP + ks2 * 32 + g * 8];
          accT4[0][kb] = __builtin_amdgcn_mfma_f32_16x16x32_bf16(kf, qf[0][ks2], accT4[0][kb], 0,0,0);
          accT4[1][kb] = __builtin_amdgcn_mfma_f32_16x16x32_bf16(kf, qf[1][ks2], accT4[1][kb], 0,0,0);
        }
      }
      __builtin_amdgcn_s_setprio(0);

      // ---- static softmax: P = exp2(S), pack to bf16 pairs (lane-local) ----
      unsigned int up[2][4][2];
#pragma unroll
      for (int t = 0; t < 2; ++t)
#pragma unroll
        for (int kb = 0; kb < 4; ++kb) {
          const float p0 = __builtin_amdgcn_exp2f(accT4[t][kb][0]);
          const float p1 = __builtin_amdgcn_exp2f(accT4[t][kb][1]);
          const float p2 = __builtin_amdgcn_exp2f(accT4[t][kb][2]);
          const float p3 = __builtin_amdgcn_exp2f(accT4[t][kb][3]);
          l_part[t] += (p0 + p1) + (p2 + p3);
          up[t][kb][0] = pk2(p0, p1);
          up[t][kb][1] = pk2(p2, p3);
        }

      // ---- O^T += V^T P^T ; one vf read feeds both q-sub-tiles ----
#pragma unroll
      for (int ks2 = 0; ks2 < 2; ++ks2) {
        short8 pa[2];
#pragma unroll
        for (int t = 0; t < 2; ++t) {
          u32x4 wv;
          wv.x = up[t][2 * ks2][0];
          wv.y = up[t][2 * ks2][1];
          wv.z = up[t][2 * ks2 + 1][0];
          wv.w = up[t][2 * ks2 + 1][1];
          pa[t] = __builtin_bit_cast(short8, wv);
        }
        __builtin_amdgcn_s_setprio(1);
#pragma unroll
        for (int db = 0; db < 4; ++db) {
          const short8 vf = *(const short8*)
              &Vs[(db * 16 + c) * VP + st * 64 + ks2 * 32 + g * 8];
          accO4[0][db] = __builtin_amdgcn_mfma_f32_16x16x32_bf16(vf, pa[0], accO4[0][db], 0,0,0);
          accO4[1][db] = __builtin_amdgcn_mfma_f32_16x16x32_bf16(vf, pa[1], accO4[1][db], 0,0,0);
        }
        __builtin_amdgcn_s_setprio(0);
      }
    }
  }

  // ---- epilogue: reduce l across the 4 g-groups, normalize, store ----
#pragma unroll
  for (int t = 0; t < 2; ++t) {
    float l = l_part[t];
    l += __shfl_xor(l, 16);
    l += __shfl_xor(l, 32);
    const float inv = 1.f / l;
    const size_t rb = (size_t)qrow[t] * Cc + h * Dd;
#pragma unroll
    for (int db = 0; db < 4; ++db) {
      const int d0 = db * 16 + g * 4;
      ushort4 uh, ul;
#pragma unroll
      for (int e = 0; e < 4; ++e) {
        const float o = accO4[t][db][e] * inv;
        const ushort hb = f2bf(o);
        ((ushort*)&uh)[e] = hb;
        ((ushort*)&ul)[e] = f2bf(o - bf2f(hb));
      }
      *(ushort4*)&ohi[rb + d0] = uh;
      *(ushort4*)&olo[rb + d0] = ul;
    }
  }
}

// ---------------------------------------------------------------------------
extern "C" void kernel_launch(void* const* d_in, const int* in_sizes, int n_in,
                              void* d_out, int out_size, void* d_ws, size_t ws_size,
                              hipStream_t stream)
{
  const float* x     = (const float*)d_in[0];  // (B,N,C)
  const float* q     = (const float*)d_in[1];  // (TQ,C)
  const float* Wq    = (const float*)d_in[2];  // (C,C)
  const float* Wkv   = (const float*)d_in[3];  // (2C,C): rows [0,C)=Wk, [C,2C)=Wv
  const float* Wproj = (const float*)d_in[4];  // (C,C)
  const float* bproj = (const float*)d_in[5];  // (C)

  const int TQ = in_sizes[1] / Cc;   // 11776 (multiple of 128)
  const int BN = in_sizes[0] / Cc;   // 16384

  const size_t szQ = (size_t)TQ * Cc * 2;
  const size_t szX = (size_t)BN * Cc * 2;

  // workspace carve (68 MB total)
  char* p = (char*)d_ws;
  ushort* q_hi  = (ushort*)p;  p += szQ;       // 12 MB
  ushort* k_bf  = (ushort*)p;  p += szX;       // 16 MB
  ushort* v_t   = (ushort*)p;  p += szX;       // 16 MB
  ushort* at_hi = (ushort*)p;  p += szQ;       // 12 MB
  ushort* at_lo = (ushort*)p;                  // 12 MB

  // 1) q_hi = bf16(C2SCALE * (q @ Wq^T)), 1-term, fused f32 staging
  mfma_nt2_kernel<2, 1, true, true><<<dim3(Cc/128, TQ/128), 256, 0, stream>>>(
      q, nullptr, Wq, nullptr, nullptr, nullptr, q_hi, Cc);
  // 2) fused: k_bf = bf16(x @ Wk^T) AND v_t = bf16(x @ Wv^T)^T
  mfma_kv_fused_kernel<<<dim3(Cc/128, BN/128), 256, 0, stream>>>(
      x, Wkv, k_bf, v_t, BN);
  // 3) attention: lane-local P, issue-early staging
  attn_mfma13_kernel<<<dim3(64 * 15), 256, 0, stream>>>(
      q_hi, k_bf, v_t, at_hi, at_lo);
  // 4) out = attno @ Wproj^T + bproj, 3-term (A = bf16 hi/lo, B = f32 split)
  mfma_nt2_kernel<0, 3, false, true><<<dim3(Cc/128, TQ/128), 256, 0, stream>>>(
      at_hi, at_lo, Wproj, nullptr, bproj, (float*)d_out, nullptr, Cc);
}

// Round 18
// 174.161 us; speedup vs baseline: 1.7393x; 1.7393x over previous
//
#include <hip/hip_runtime.h>
#include <hip/hip_bf16.h>
#include <math.h>

// Problem constants (fixed by the reference):
constexpr int Cc = 512;   // channels
constexpr int Hh = 8;     // heads
constexpr int Dd = 64;    // head dim
constexpr int Nn = 2048;  // kv length
constexpr int Bb = 8;     // batch
constexpr int GK = 512;   // K dim of every GEMM here

typedef __attribute__((ext_vector_type(8))) short short8;
typedef __attribute__((ext_vector_type(4))) float f32x4;
typedef __attribute__((ext_vector_type(4))) unsigned int u32x4;
typedef __attribute__((ext_vector_type(2))) unsigned int u32x2;

// scale * log2(e) folded into Q at projection time
#define C2SCALE 0.1803368801f

static __device__ __forceinline__ ushort f2bf(float v) {
  __hip_bfloat16 h = __float2bfloat16(v);
  return *reinterpret_cast<ushort*>(&h);
}
static __device__ __forceinline__ float bf2f(ushort u) {
  __hip_bfloat16 h = *reinterpret_cast<__hip_bfloat16*>(&u);
  return __bfloat162float(h);
}
// pack two f32 -> u32 of two bf16 (f0 low, f1 high), RNE via f2bf
static __device__ __forceinline__ unsigned int pk2(float f0, float f1) {
  return (unsigned int)f2bf(f0) | ((unsigned int)f2bf(f1) << 16);
}

// ---------------------------------------------------------------------------
// MFMA GEMM with fused dtype handling (proven): C = A B^T (+bias).
// Used for Q (MODE 2, 1-term) and proj (MODE 0, 3-term).
// ---------------------------------------------------------------------------
template <int MODE, int TERMS, bool AF32, bool BF32>
__global__ __launch_bounds__(256) void mfma_nt2_kernel(
    const void* __restrict__ A0p, const void* __restrict__ A1p,
    const void* __restrict__ B0p, const void* __restrict__ B1p,
    const float* __restrict__ bias, float* __restrict__ Cf,
    ushort* __restrict__ Chi, int Nc)
{
  __shared__ ushort lAh[128 * 32];
  __shared__ ushort lBh[128 * 32];
  __shared__ ushort lAl[TERMS == 3 ? 128 * 32 : 1];
  __shared__ ushort lBl[TERMS == 3 ? 128 * 32 : 1];

  const int tid = threadIdx.x;
  const int w = tid >> 6, lane = tid & 63;
  const int c = lane & 15, g = lane >> 4;
  const int wr = (w >> 1) * 64, wc = (w & 1) * 64;
  const int m0 = blockIdx.y * 128, n0 = blockIdx.x * 128;
  const int sr = tid >> 2;          // staging row 0..63
  const int sk = (tid & 3) * 8;     // staging k-offset (elements)

  short8 rAh[2], rAl[2], rBh[2], rBl[2];

  auto ldf32 = [&](const float* F, size_t idx, short8& h, short8& l) {
    const float4 f0 = *(const float4*)(F + idx);
    const float4 f1 = *(const float4*)(F + idx + 4);
    const float vv[8] = {f0.x, f0.y, f0.z, f0.w, f1.x, f1.y, f1.z, f1.w};
#pragma unroll
    for (int j = 0; j < 8; ++j) {
      const ushort hb = f2bf(vv[j]);
      ((ushort*)&h)[j] = hb;
      if (TERMS == 3) ((ushort*)&l)[j] = f2bf(vv[j] - bf2f(hb));
    }
  };

  auto loadA = [&](int k0) {
#pragma unroll
    for (int hf = 0; hf < 2; ++hf) {
      const size_t idx = (size_t)(m0 + sr + hf * 64) * GK + k0 + sk;
      if (AF32) {
        ldf32((const float*)A0p, idx, rAh[hf], rAl[hf]);
      } else {
        rAh[hf] = *(const short8*)((const ushort*)A0p + idx);
        if (TERMS == 3) rAl[hf] = *(const short8*)((const ushort*)A1p + idx);
      }
    }
  };
  auto loadB = [&](int k0) {
#pragma unroll
    for (int hf = 0; hf < 2; ++hf) {
      const size_t idx = (size_t)(n0 + sr + hf * 64) * GK + k0 + sk;
      if (BF32) {
        ldf32((const float*)B0p, idx, rBh[hf], rBl[hf]);
      } else {
        rBh[hf] = *(const short8*)((const ushort*)B0p + idx);
        if (TERMS == 3) rBl[hf] = *(const short8*)((const ushort*)B1p + idx);
      }
    }
  };

  f32x4 acc[4][4] = {};
  loadA(0);
  loadB(0);

  for (int k0 = 0; k0 < GK; k0 += 32) {
    __syncthreads();
    *(short8*)&lAh[sr * 32 + sk]        = rAh[0];
    *(short8*)&lAh[(sr + 64) * 32 + sk] = rAh[1];
    *(short8*)&lBh[sr * 32 + sk]        = rBh[0];
    *(short8*)&lBh[(sr + 64) * 32 + sk] = rBh[1];
    if (TERMS == 3) {
      *(short8*)&lAl[sr * 32 + sk]        = rAl[0];
      *(short8*)&lAl[(sr + 64) * 32 + sk] = rAl[1];
      *(short8*)&lBl[sr * 32 + sk]        = rBl[0];
      *(short8*)&lBl[(sr + 64) * 32 + sk] = rBl[1];
    }
    __syncthreads();
    if (k0 + 32 < GK) { loadA(k0 + 32); loadB(k0 + 32); }  // T14 issue-early

    short8 ah[4], al[4], bh[4], bl[4];
#pragma unroll
    for (int i = 0; i < 4; ++i) {
      const int ar = (wr + i * 16 + c) * 32 + g * 8;
      const int br = (wc + i * 16 + c) * 32 + g * 8;
      ah[i] = *(const short8*)&lAh[ar];
      bh[i] = *(const short8*)&lBh[br];
      if (TERMS == 3) {
        al[i] = *(const short8*)&lAl[ar];
        bl[i] = *(const short8*)&lBl[br];
      }
    }
#pragma unroll
    for (int mi = 0; mi < 4; ++mi)
#pragma unroll
      for (int nj = 0; nj < 4; ++nj) {
        if (TERMS == 3) {
          acc[mi][nj] = __builtin_amdgcn_mfma_f32_16x16x32_bf16(ah[mi], bl[nj], acc[mi][nj], 0,0,0);
          acc[mi][nj] = __builtin_amdgcn_mfma_f32_16x16x32_bf16(al[mi], bh[nj], acc[mi][nj], 0,0,0);
        }
        acc[mi][nj] = __builtin_amdgcn_mfma_f32_16x16x32_bf16(ah[mi], bh[nj], acc[mi][nj], 0,0,0);
      }
  }

#pragma unroll
  for (int mi = 0; mi < 4; ++mi) {
#pragma unroll
    for (int r = 0; r < 4; ++r) {
      const size_t rb = (size_t)(m0 + wr + mi * 16 + g * 4 + r) * Nc;
#pragma unroll
      for (int nj = 0; nj < 4; ++nj) {
        const int col = n0 + wc + nj * 16 + c;
        const float v = acc[mi][nj][r];
        if (MODE == 0) {
          Cf[rb + col] = v + bias[col];
        } else if (MODE == 1) {
          Chi[rb + col] = f2bf(v);
        } else {
          Chi[rb + col] = f2bf(v * C2SCALE);   // Q pre-scaled for exp2 domain
        }
      }
    }
  }
}

// ---------------------------------------------------------------------------
// Fused K+V projection GEMM (R17, proven win): stages each x-tile ONCE,
//   k = x @ Wk^T -> k_bf (BN, C) bf16; v = x @ Wv^T -> v_t (C, BN) bf16
// via transpose-through-LDS epilogue. Same k-order => identical rounding.
// ---------------------------------------------------------------------------
__global__ __launch_bounds__(256, 2) void mfma_kv_fused_kernel(
    const float* __restrict__ x, const float* __restrict__ Wkv,
    ushort* __restrict__ kbf, ushort* __restrict__ vtb, int BN)
{
  __shared__ ushort smem[128 * 136];       // 34.8 KB
  ushort* lA   = smem;                     // 128*32 (staging phase)
  ushort* lBk  = smem + 128 * 32;
  ushort* lBv  = smem + 2 * 128 * 32;
  ushort* tbuf = smem;                     // 128*136 (epilogue phase)

  const int tid = threadIdx.x;
  const int w = tid >> 6, lane = tid & 63;
  const int c = lane & 15, g = lane >> 4;
  const int wr = (w >> 1) * 64, wc = (w & 1) * 64;
  const int n0 = blockIdx.x * 128, m0 = blockIdx.y * 128;
  const int sr = tid >> 2, sk = (tid & 3) * 8;

  auto cvt8 = [&](const float* F, size_t idx) -> short8 {
    const float4 f0 = *(const float4*)(F + idx);
    const float4 f1 = *(const float4*)(F + idx + 4);
    const float vv[8] = {f0.x, f0.y, f0.z, f0.w, f1.x, f1.y, f1.z, f1.w};
    short8 h;
#pragma unroll
    for (int j = 0; j < 8; ++j) ((ushort*)&h)[j] = f2bf(vv[j]);
    return h;
  };

  short8 rA[2], rBk[2], rBv[2];
  auto loadAll = [&](int k0) {
#pragma unroll
    for (int hf = 0; hf < 2; ++hf) {
      rA[hf]  = cvt8(x,   (size_t)(m0 + sr + hf * 64) * GK + k0 + sk);
      rBk[hf] = cvt8(Wkv, (size_t)(n0 + sr + hf * 64) * GK + k0 + sk);
      rBv[hf] = cvt8(Wkv, (size_t)(512 + n0 + sr + hf * 64) * GK + k0 + sk);
    }
  };

  f32x4 ak[4][4] = {};
  f32x4 av[4][4] = {};
  loadAll(0);

  for (int k0 = 0; k0 < GK; k0 += 32) {
    __syncthreads();
    *(short8*)&lA[sr * 32 + sk]         = rA[0];
    *(short8*)&lA[(sr + 64) * 32 + sk]  = rA[1];
    *(short8*)&lBk[sr * 32 + sk]        = rBk[0];
    *(short8*)&lBk[(sr + 64) * 32 + sk] = rBk[1];
    *(short8*)&lBv[sr * 32 + sk]        = rBv[0];
    *(short8*)&lBv[(sr + 64) * 32 + sk] = rBv[1];
    __syncthreads();
    if (k0 + 32 < GK) loadAll(k0 + 32);   // T14 issue-early

    short8 a[4], bk[4], bv[4];
#pragma unroll
    for (int i = 0; i < 4; ++i) {
      const int ar = (wr + i * 16 + c) * 32 + g * 8;
      const int br = (wc + i * 16 + c) * 32 + g * 8;
      a[i]  = *(const short8*)&lA[ar];
      bk[i] = *(const short8*)&lBk[br];
      bv[i] = *(const short8*)&lBv[br];
    }
#pragma unroll
    for (int mi = 0; mi < 4; ++mi)
#pragma unroll
      for (int nj = 0; nj < 4; ++nj) {
        ak[mi][nj] = __builtin_amdgcn_mfma_f32_16x16x32_bf16(a[mi], bk[nj], ak[mi][nj], 0,0,0);
        av[mi][nj] = __builtin_amdgcn_mfma_f32_16x16x32_bf16(a[mi], bv[nj], av[mi][nj], 0,0,0);
      }
  }

  // ---- K epilogue: normal bf16 store ----
#pragma unroll
  for (int mi = 0; mi < 4; ++mi)
#pragma unroll
    for (int r = 0; r < 4; ++r) {
      const size_t rb = (size_t)(m0 + wr + mi * 16 + g * 4 + r) * Cc;
#pragma unroll
      for (int nj = 0; nj < 4; ++nj)
        kbf[rb + n0 + wc + nj * 16 + c] = f2bf(ak[mi][nj][r]);
    }

  // ---- V epilogue: transpose through LDS, coalesced v_t store ----
  __syncthreads();   // staging LDS dead (all frags consumed into regs)
#pragma unroll
  for (int mi = 0; mi < 4; ++mi)
#pragma unroll
    for (int r = 0; r < 4; ++r) {
      const int tl = wr + mi * 16 + g * 4 + r;   // token local
#pragma unroll
      for (int nj = 0; nj < 4; ++nj) {
        const int dl = wc + nj * 16 + c;         // d local
        tbuf[dl * 136 + tl] = f2bf(av[mi][nj][r]);
      }
    }
  __syncthreads();
#pragma unroll
  for (int it = 0; it < 8; ++it) {
    const int idx = tid + it * 256;
    const int row = idx >> 4;            // d local 0..127
    const int c8 = (idx & 15) * 8;       // token chunk
    *(short8*)&vtb[(size_t)(n0 + row) * BN + m0 + c8] =
        *(const short8*)&tbuf[row * 136 + c8];
  }
}

// ---------------------------------------------------------------------------
// Swapped-operand MFMA flash attention (R16, proven 105.9us): 16x16x32, two
// 16-row q-sub-tiles per wave sharing each K/V fragment read; lane-local P;
// STATIC softmax in exp2 domain; V sigma-permuted via global fetch; direct
// global->LDS staging (NO reg-held issue-early — it spills at this bound).
// Block = 128 q-rows x 1 (b,h), 4 waves x 32 q-rows; 128-key chunks.
// ---------------------------------------------------------------------------
__global__ __launch_bounds__(256, 4) void attn_mfma12_kernel(
    const ushort* __restrict__ qhi,  // (TQ, C) bf16, pre-scaled by C2SCALE
    const ushort* __restrict__ kbf,  // (B*N, C) bf16
    const ushort* __restrict__ vtb,  // (C, B*N) bf16  (V^T)
    ushort* __restrict__ ohi,        // (TQ, C) bf16 hi
    ushort* __restrict__ olo)        // (TQ, C) bf16 lo
{
  // Q_LENGTHS = 1024 + 128*b ; cumulative offsets:
  constexpr int QOFF[8] = {0, 1024, 2176, 3456, 4864, 6400, 8064, 9856};

  const int lin = blockIdx.x;
  const int b  = lin & 7;            // lin%8=b -> batch pinned per XCD
  const int h  = (lin >> 3) & 7;
  const int qt = lin >> 6;

  const int Lb  = 1024 + 128 * b;
  const int off = QOFF[b];
  if (qt * 128 >= Lb) return;        // uniform; lengths are %128==0

  constexpr int KP = 72;             // K row stride (bf16)
  constexpr int VP = 136;            // V row stride (bf16)
  constexpr int NC = Nn / 128;       // 16 chunks of 128 keys
  __shared__ ushort Ks[128 * KP];    // [key][d]
  __shared__ ushort Vs[64 * VP];     // [d][sigma(key) within 128]

  const int tid = threadIdx.x;
  const int lane = tid & 63;
  const int w = tid >> 6;            // wave 0..3 -> q-rows [w*32, w*32+32)
  const int c = lane & 15;           // q (B-col) / key-row (A) / d-row (PV A)
  const int g = (lane >> 4) & 3;     // k-chunk selector

  // Q fragments for two 16-row sub-tiles t: rows w*32 + t*16 + c
  short8 qf[2][2];
  int qrow[2];
#pragma unroll
  for (int t = 0; t < 2; ++t) {
    qrow[t] = off + qt * 128 + w * 32 + t * 16 + c;
    const size_t base = (size_t)qrow[t] * Cc + h * Dd + g * 8;
    qf[t][0] = *(const short8*)(qhi + base);
    qf[t][1] = *(const short8*)(qhi + base + 32);
  }

  float l_part[2] = {0.f, 0.f};      // per-lane partial sums; reduced at end
  f32x4 accO4[2][4] = {};            // O^T per tile: rows d=db*16+g*4+r, col q=c

  const size_t kbase = (size_t)b * Nn * Cc + h * Dd;
  const size_t vbase = (size_t)h * Dd * (Bb * Nn) + (size_t)b * Nn;

  for (int ch = 0; ch < NC; ++ch) {
    __syncthreads();   // previous chunk's LDS reads complete
    // stage K: 128 keys x 128B (4 short8 per thread, 256 threads)
#pragma unroll
    for (int it = 0; it < 4; ++it) {
      const int i = tid + it * 256;
      const int row = i >> 3, c8 = (i & 7) * 8;
      *(short8*)&Ks[row * KP + c8] =
          *(const short8*)&kbf[kbase + (size_t)(ch * 128 + row) * Cc + c8];
    }
    // stage V: linear b128 LDS write; sigma^-1 applied to the GLOBAL fetch.
#pragma unroll
    for (int it = 0; it < 4; ++it) {
      const int i = tid + it * 256;
      const int row = i >> 4, c8 = (i & 15) * 8;
      const int kb1 = (c8 & ~31) | (((c8 >> 3) & 3) << 2);
      const size_t gb = vbase + (size_t)row * (Bb * Nn) + ch * 128;
      const u32x2 vlo = *(const u32x2*)&vtb[gb + kb1];
      const u32x2 vhi = *(const u32x2*)&vtb[gb + kb1 + 16];
      u32x4 vv;
      vv[0] = vlo[0]; vv[1] = vlo[1];
      vv[2] = vhi[0]; vv[3] = vhi[1];
      *(short8*)&Vs[row * VP + c8] = __builtin_bit_cast(short8, vv);
    }
    __syncthreads();

#pragma unroll
    for (int st = 0; st < 2; ++st) {
      // ---- S^T = K Q^T : one kf read feeds both q-sub-tiles ----
      f32x4 accT4[2][4] = {};
      __builtin_amdgcn_s_setprio(1);
#pragma unroll
      for (int ks2 = 0; ks2 < 2; ++ks2) {
#pragma unroll
        for (int kb = 0; kb < 4; ++kb) {
          const short8 kf = *(const short8*)
              &Ks[(st * 64 + kb * 16 + c) * KP + ks2 * 32 + g * 8];
          accT4[0][kb] = __builtin_amdgcn_mfma_f32_16x16x32_bf16(kf, qf[0][ks2], accT4[0][kb], 0,0,0);
          accT4[1][kb] = __builtin_amdgcn_mfma_f32_16x16x32_bf16(kf, qf[1][ks2], accT4[1][kb], 0,0,0);
        }
      }
      __builtin_amdgcn_s_setprio(0);

      // ---- static softmax: P = exp2(S), pack to bf16 pairs (lane-local) ----
      unsigned int up[2][4][2];
#pragma unroll
      for (int t = 0; t < 2; ++t)
#pragma unroll
        for (int kb = 0; kb < 4; ++kb) {
          const float p0 = __builtin_amdgcn_exp2f(accT4[t][kb][0]);
          const float p1 = __builtin_amdgcn_exp2f(accT4[t][kb][1]);
          const float p2 = __builtin_amdgcn_exp2f(accT4[t][kb][2]);
          const float p3 = __builtin_amdgcn_exp2f(accT4[t][kb][3]);
          l_part[t] += (p0 + p1) + (p2 + p3);
          up[t][kb][0] = pk2(p0, p1);
          up[t][kb][1] = pk2(p2, p3);
        }

      // ---- O^T += V^T P^T ; one vf read feeds both q-sub-tiles ----
#pragma unroll
      for (int ks2 = 0; ks2 < 2; ++ks2) {
        short8 pa[2];
#pragma unroll
        for (int t = 0; t < 2; ++t) {
          u32x4 wv;
          wv.x = up[t][2 * ks2][0];
          wv.y = up[t][2 * ks2][1];
          wv.z = up[t][2 * ks2 + 1][0];
          wv.w = up[t][2 * ks2 + 1][1];
          pa[t] = __builtin_bit_cast(short8, wv);
        }
        __builtin_amdgcn_s_setprio(1);
#pragma unroll
        for (int db = 0; db < 4; ++db) {
          const short8 vf = *(const short8*)
              &Vs[(db * 16 + c) * VP + st * 64 + ks2 * 32 + g * 8];
          accO4[0][db] = __builtin_amdgcn_mfma_f32_16x16x32_bf16(vf, pa[0], accO4[0][db], 0,0,0);
          accO4[1][db] = __builtin_amdgcn_mfma_f32_16x16x32_bf16(vf, pa[1], accO4[1][db], 0,0,0);
        }
        __builtin_amdgcn_s_setprio(0);
      }
    }
  }

  // ---- epilogue: reduce l across the 4 g-groups, normalize, store ----
#pragma unroll
  for (int t = 0; t < 2; ++t) {
    float l = l_part[t];
    l += __shfl_xor(l, 16);
    l += __shfl_xor(l, 32);
    const float inv = 1.f / l;
    const size_t rb = (size_t)qrow[t] * Cc + h * Dd;
#pragma unroll
    for (int db = 0; db < 4; ++db) {
      const int d0 = db * 16 + g * 4;
      ushort4 uh, ul;
#pragma unroll
      for (int e = 0; e < 4; ++e) {
        const float o = accO4[t][db][e] * inv;
        const ushort hb = f2bf(o);
        ((ushort*)&uh)[e] = hb;
        ((ushort*)&ul)[e] = f2bf(o - bf2f(hb));
      }
      *(ushort4*)&ohi[rb + d0] = uh;
      *(ushort4*)&olo[rb + d0] = ul;
    }
  }
}

// ---------------------------------------------------------------------------
extern "C" void kernel_launch(void* const* d_in, const int* in_sizes, int n_in,
                              void* d_out, int out_size, void* d_ws, size_t ws_size,
                              hipStream_t stream)
{
  const float* x     = (const float*)d_in[0];  // (B,N,C)
  const float* q     = (const float*)d_in[1];  // (TQ,C)
  const float* Wq    = (const float*)d_in[2];  // (C,C)
  const float* Wkv   = (const float*)d_in[3];  // (2C,C): rows [0,C)=Wk, [C,2C)=Wv
  const float* Wproj = (const float*)d_in[4];  // (C,C)
  const float* bproj = (const float*)d_in[5];  // (C)

  const int TQ = in_sizes[1] / Cc;   // 11776 (multiple of 128)
  const int BN = in_sizes[0] / Cc;   // 16384

  const size_t szQ = (size_t)TQ * Cc * 2;
  const size_t szX = (size_t)BN * Cc * 2;

  // workspace carve (68 MB total)
  char* p = (char*)d_ws;
  ushort* q_hi  = (ushort*)p;  p += szQ;       // 12 MB
  ushort* k_bf  = (ushort*)p;  p += szX;       // 16 MB
  ushort* v_t   = (ushort*)p;  p += szX;       // 16 MB
  ushort* at_hi = (ushort*)p;  p += szQ;       // 12 MB
  ushort* at_lo = (ushort*)p;                  // 12 MB

  // 1) q_hi = bf16(C2SCALE * (q @ Wq^T)), 1-term, fused f32 staging
  mfma_nt2_kernel<2, 1, true, true><<<dim3(Cc/128, TQ/128), 256, 0, stream>>>(
      q, nullptr, Wq, nullptr, nullptr, nullptr, q_hi, Cc);
  // 2) fused: k_bf = bf16(x @ Wk^T) AND v_t = bf16(x @ Wv^T)^T
  mfma_kv_fused_kernel<<<dim3(Cc/128, BN/128), 256, 0, stream>>>(
      x, Wkv, k_bf, v_t, BN);
  // 3) attention: R16 proven kernel (direct staging, no spills)
  attn_mfma12_kernel<<<dim3(64 * 15), 256, 0, stream>>>(
      q_hi, k_bf, v_t, at_hi, at_lo);
  // 4) out = attno @ Wproj^T + bproj, 3-term (A = bf16 hi/lo, B = f32 split)
  mfma_nt2_kernel<0, 3, false, true><<<dim3(Cc/128, TQ/128), 256, 0, stream>>>(
      at_hi, at_lo, Wproj, nullptr, bproj, (float*)d_out, nullptr, Cc);
}

// Round 19
// 159.953 us; speedup vs baseline: 1.8938x; 1.0888x over previous
//
#include <hip/hip_runtime.h>
#include <hip/hip_bf16.h>
#include <math.h>

// Problem constants (fixed by the reference):
constexpr int Cc = 512;   // channels
constexpr int Hh = 8;     // heads
constexpr int Dd = 64;    // head dim
constexpr int Nn = 2048;  // kv length
constexpr int Bb = 8;     // batch
constexpr int GK = 512;   // K dim of every GEMM here

typedef __attribute__((ext_vector_type(8))) short short8;
typedef __attribute__((ext_vector_type(4))) float f32x4;
typedef __attribute__((ext_vector_type(4))) unsigned int u32x4;
typedef __attribute__((ext_vector_type(2))) unsigned int u32x2;

// scale * log2(e) folded into Q at projection time
#define C2SCALE 0.1803368801f

static __device__ __forceinline__ ushort f2bf(float v) {
  __hip_bfloat16 h = __float2bfloat16(v);
  return *reinterpret_cast<ushort*>(&h);
}
static __device__ __forceinline__ float bf2f(ushort u) {
  __hip_bfloat16 h = *reinterpret_cast<__hip_bfloat16*>(&u);
  return __bfloat162float(h);
}
// pack two f32 -> u32 of two bf16 (f0 low, f1 high), RNE via f2bf
static __device__ __forceinline__ unsigned int pk2(float f0, float f1) {
  return (unsigned int)f2bf(f0) | ((unsigned int)f2bf(f1) << 16);
}

// ---------------------------------------------------------------------------
// Proj GEMM (proven, used for out-projection): C = A B^T + bias,
// A = bf16 hi/lo pair, B = f32 (split in staging), 3-term f32-accurate.
// ---------------------------------------------------------------------------
__global__ __launch_bounds__(256) void mfma_proj_kernel(
    const ushort* __restrict__ Ah, const ushort* __restrict__ Al,
    const float* __restrict__ Bf, const float* __restrict__ bias,
    float* __restrict__ Cf, int Nc)
{
  __shared__ ushort lAh[128 * 32];
  __shared__ ushort lBh[128 * 32];
  __shared__ ushort lAl[128 * 32];
  __shared__ ushort lBl[128 * 32];

  const int tid = threadIdx.x;
  const int w = tid >> 6, lane = tid & 63;
  const int c = lane & 15, g = lane >> 4;
  const int wr = (w >> 1) * 64, wc = (w & 1) * 64;
  const int m0 = blockIdx.y * 128, n0 = blockIdx.x * 128;
  const int sr = tid >> 2;
  const int sk = (tid & 3) * 8;

  short8 rAh[2], rAl[2], rBh[2], rBl[2];

  auto ldf32 = [&](const float* F, size_t idx, short8& h, short8& l) {
    const float4 f0 = *(const float4*)(F + idx);
    const float4 f1 = *(const float4*)(F + idx + 4);
    const float vv[8] = {f0.x, f0.y, f0.z, f0.w, f1.x, f1.y, f1.z, f1.w};
#pragma unroll
    for (int j = 0; j < 8; ++j) {
      const ushort hb = f2bf(vv[j]);
      ((ushort*)&h)[j] = hb;
      ((ushort*)&l)[j] = f2bf(vv[j] - bf2f(hb));
    }
  };

  auto loadAB = [&](int k0) {
#pragma unroll
    for (int hf = 0; hf < 2; ++hf) {
      const size_t ia = (size_t)(m0 + sr + hf * 64) * GK + k0 + sk;
      const size_t ib = (size_t)(n0 + sr + hf * 64) * GK + k0 + sk;
      rAh[hf] = *(const short8*)(Ah + ia);
      rAl[hf] = *(const short8*)(Al + ia);
      ldf32(Bf, ib, rBh[hf], rBl[hf]);
    }
  };

  f32x4 acc[4][4] = {};
  loadAB(0);

  for (int k0 = 0; k0 < GK; k0 += 32) {
    __syncthreads();
    *(short8*)&lAh[sr * 32 + sk]        = rAh[0];
    *(short8*)&lAh[(sr + 64) * 32 + sk] = rAh[1];
    *(short8*)&lBh[sr * 32 + sk]        = rBh[0];
    *(short8*)&lBh[(sr + 64) * 32 + sk] = rBh[1];
    *(short8*)&lAl[sr * 32 + sk]        = rAl[0];
    *(short8*)&lAl[(sr + 64) * 32 + sk] = rAl[1];
    *(short8*)&lBl[sr * 32 + sk]        = rBl[0];
    *(short8*)&lBl[(sr + 64) * 32 + sk] = rBl[1];
    __syncthreads();
    if (k0 + 32 < GK) loadAB(k0 + 32);  // T14 issue-early

    short8 ah[4], al[4], bh[4], bl[4];
#pragma unroll
    for (int i = 0; i < 4; ++i) {
      const int ar = (wr + i * 16 + c) * 32 + g * 8;
      const int br = (wc + i * 16 + c) * 32 + g * 8;
      ah[i] = *(const short8*)&lAh[ar];
      bh[i] = *(const short8*)&lBh[br];
      al[i] = *(const short8*)&lAl[ar];
      bl[i] = *(const short8*)&lBl[br];
    }
#pragma unroll
    for (int mi = 0; mi < 4; ++mi)
#pragma unroll
      for (int nj = 0; nj < 4; ++nj) {
        acc[mi][nj] = __builtin_amdgcn_mfma_f32_16x16x32_bf16(ah[mi], bl[nj], acc[mi][nj], 0,0,0);
        acc[mi][nj] = __builtin_amdgcn_mfma_f32_16x16x32_bf16(al[mi], bh[nj], acc[mi][nj], 0,0,0);
        acc[mi][nj] = __builtin_amdgcn_mfma_f32_16x16x32_bf16(ah[mi], bh[nj], acc[mi][nj], 0,0,0);
      }
  }

#pragma unroll
  for (int mi = 0; mi < 4; ++mi)
#pragma unroll
    for (int r = 0; r < 4; ++r) {
      const size_t rb = (size_t)(m0 + wr + mi * 16 + g * 4 + r) * Nc;
#pragma unroll
      for (int nj = 0; nj < 4; ++nj) {
        const int col = n0 + wc + nj * 16 + c;
        Cf[rb + col] = acc[mi][nj][r] + bias[col];
      }
    }
}

// ---------------------------------------------------------------------------
// Merged Q + K + V projections, one grid (Q tail overlaps KV blocks).
//  bid < NQB : q_hi = bf16(C2SCALE * (q @ Wq^T))            (Q path)
//  else      : k_bf = bf16(x @ Wk^T), v_t = bf16(x @ Wv^T)^T (fused KV path)
// Both 1-term bf16; KV path has transpose-through-LDS V epilogue (R17 win).
// ---------------------------------------------------------------------------
__global__ __launch_bounds__(256, 2) void proj_qkv_kernel(
    const float* __restrict__ qin, const float* __restrict__ Wq,
    const float* __restrict__ x, const float* __restrict__ Wkv,
    ushort* __restrict__ qhi, ushort* __restrict__ kbf,
    ushort* __restrict__ vtb, int TQ, int BN)
{
  __shared__ ushort smem[128 * 136];       // 34.8 KB (KV path max)

  const int tid = threadIdx.x;
  const int w = tid >> 6, lane = tid & 63;
  const int c = lane & 15, g = lane >> 4;
  const int wr = (w >> 1) * 64, wc = (w & 1) * 64;
  const int sr = tid >> 2, sk = (tid & 3) * 8;
  const int NQB = (TQ / 128) * (Cc / 128);   // 368
  const int bid = blockIdx.x;

  auto cvt8 = [&](const float* F, size_t idx) -> short8 {
    const float4 f0 = *(const float4*)(F + idx);
    const float4 f1 = *(const float4*)(F + idx + 4);
    const float vv[8] = {f0.x, f0.y, f0.z, f0.w, f1.x, f1.y, f1.z, f1.w};
    short8 h;
#pragma unroll
    for (int j = 0; j < 8; ++j) ((ushort*)&h)[j] = f2bf(vv[j]);
    return h;
  };

  if (bid < NQB) {
    // ---------------- Q path ----------------
    const int m0 = (bid >> 2) * 128;
    const int n0 = (bid & 3) * 128;
    ushort* lA = smem;                 // 128*32
    ushort* lB = smem + 128 * 32;

    short8 rA[2], rB[2];
    auto loadQ = [&](int k0) {
#pragma unroll
      for (int hf = 0; hf < 2; ++hf) {
        rA[hf] = cvt8(qin, (size_t)(m0 + sr + hf * 64) * GK + k0 + sk);
        rB[hf] = cvt8(Wq,  (size_t)(n0 + sr + hf * 64) * GK + k0 + sk);
      }
    };

    f32x4 acc[4][4] = {};
    loadQ(0);
    for (int k0 = 0; k0 < GK; k0 += 32) {
      __syncthreads();
      *(short8*)&lA[sr * 32 + sk]        = rA[0];
      *(short8*)&lA[(sr + 64) * 32 + sk] = rA[1];
      *(short8*)&lB[sr * 32 + sk]        = rB[0];
      *(short8*)&lB[(sr + 64) * 32 + sk] = rB[1];
      __syncthreads();
      if (k0 + 32 < GK) loadQ(k0 + 32);

      short8 a[4], bb[4];
#pragma unroll
      for (int i = 0; i < 4; ++i) {
        a[i]  = *(const short8*)&lA[(wr + i * 16 + c) * 32 + g * 8];
        bb[i] = *(const short8*)&lB[(wc + i * 16 + c) * 32 + g * 8];
      }
#pragma unroll
      for (int mi = 0; mi < 4; ++mi)
#pragma unroll
        for (int nj = 0; nj < 4; ++nj)
          acc[mi][nj] = __builtin_amdgcn_mfma_f32_16x16x32_bf16(a[mi], bb[nj], acc[mi][nj], 0,0,0);
    }
#pragma unroll
    for (int mi = 0; mi < 4; ++mi)
#pragma unroll
      for (int r = 0; r < 4; ++r) {
        const size_t rb = (size_t)(m0 + wr + mi * 16 + g * 4 + r) * Cc;
#pragma unroll
        for (int nj = 0; nj < 4; ++nj)
          qhi[rb + n0 + wc + nj * 16 + c] = f2bf(acc[mi][nj][r] * C2SCALE);
      }
  } else {
    // ---------------- fused KV path ----------------
    const int b2 = bid - NQB;
    const int n0 = (b2 & 3) * 128;
    const int m0 = (b2 >> 2) * 128;
    ushort* lA   = smem;
    ushort* lBk  = smem + 128 * 32;
    ushort* lBv  = smem + 2 * 128 * 32;
    ushort* tbuf = smem;               // epilogue reuse

    short8 rA[2], rBk[2], rBv[2];
    auto loadAll = [&](int k0) {
#pragma unroll
      for (int hf = 0; hf < 2; ++hf) {
        rA[hf]  = cvt8(x,   (size_t)(m0 + sr + hf * 64) * GK + k0 + sk);
        rBk[hf] = cvt8(Wkv, (size_t)(n0 + sr + hf * 64) * GK + k0 + sk);
        rBv[hf] = cvt8(Wkv, (size_t)(512 + n0 + sr + hf * 64) * GK + k0 + sk);
      }
    };

    f32x4 ak[4][4] = {};
    f32x4 av[4][4] = {};
    loadAll(0);

    for (int k0 = 0; k0 < GK; k0 += 32) {
      __syncthreads();
      *(short8*)&lA[sr * 32 + sk]         = rA[0];
      *(short8*)&lA[(sr + 64) * 32 + sk]  = rA[1];
      *(short8*)&lBk[sr * 32 + sk]        = rBk[0];
      *(short8*)&lBk[(sr + 64) * 32 + sk] = rBk[1];
      *(short8*)&lBv[sr * 32 + sk]        = rBv[0];
      *(short8*)&lBv[(sr + 64) * 32 + sk] = rBv[1];
      __syncthreads();
      if (k0 + 32 < GK) loadAll(k0 + 32);

      short8 a[4], bk[4], bv[4];
#pragma unroll
      for (int i = 0; i < 4; ++i) {
        const int ar = (wr + i * 16 + c) * 32 + g * 8;
        const int br = (wc + i * 16 + c) * 32 + g * 8;
        a[i]  = *(const short8*)&lA[ar];
        bk[i] = *(const short8*)&lBk[br];
        bv[i] = *(const short8*)&lBv[br];
      }
#pragma unroll
      for (int mi = 0; mi < 4; ++mi)
#pragma unroll
        for (int nj = 0; nj < 4; ++nj) {
          ak[mi][nj] = __builtin_amdgcn_mfma_f32_16x16x32_bf16(a[mi], bk[nj], ak[mi][nj], 0,0,0);
          av[mi][nj] = __builtin_amdgcn_mfma_f32_16x16x32_bf16(a[mi], bv[nj], av[mi][nj], 0,0,0);
        }
    }

    // K epilogue: normal bf16 store
#pragma unroll
    for (int mi = 0; mi < 4; ++mi)
#pragma unroll
      for (int r = 0; r < 4; ++r) {
        const size_t rb = (size_t)(m0 + wr + mi * 16 + g * 4 + r) * Cc;
#pragma unroll
        for (int nj = 0; nj < 4; ++nj)
          kbf[rb + n0 + wc + nj * 16 + c] = f2bf(ak[mi][nj][r]);
      }

    // V epilogue: transpose through LDS, coalesced v_t store
    __syncthreads();
#pragma unroll
    for (int mi = 0; mi < 4; ++mi)
#pragma unroll
      for (int r = 0; r < 4; ++r) {
        const int tl = wr + mi * 16 + g * 4 + r;
#pragma unroll
        for (int nj = 0; nj < 4; ++nj)
          tbuf[(wc + nj * 16 + c) * 136 + tl] = f2bf(av[mi][nj][r]);
      }
    __syncthreads();
#pragma unroll
    for (int it = 0; it < 8; ++it) {
      const int idx = tid + it * 256;
      const int row = idx >> 4;
      const int c8 = (idx & 15) * 8;
      *(short8*)&vtb[(size_t)(n0 + row) * BN + m0 + c8] =
          *(const short8*)&tbuf[row * 136 + c8];
    }
  }
}

// ---------------------------------------------------------------------------
// Swapped-operand MFMA flash attention: R16 structure with 64-KEY chunks
// (LDS 35.8KB -> 18.4KB => 8 blocks/CU, 32 waves/CU at 64 VGPR).
// Accumulation key-order identical to R16/R18 -> bit-identical output.
// ---------------------------------------------------------------------------
__global__ __launch_bounds__(256, 4) void attn_mfma14_kernel(
    const ushort* __restrict__ qhi,  // (TQ, C) bf16, pre-scaled by C2SCALE
    const ushort* __restrict__ kbf,  // (B*N, C) bf16
    const ushort* __restrict__ vtb,  // (C, B*N) bf16  (V^T)
    ushort* __restrict__ ohi,        // (TQ, C) bf16 hi
    ushort* __restrict__ olo)        // (TQ, C) bf16 lo
{
  // Q_LENGTHS = 1024 + 128*b ; cumulative offsets:
  constexpr int QOFF[8] = {0, 1024, 2176, 3456, 4864, 6400, 8064, 9856};

  const int lin = blockIdx.x;
  const int b  = lin & 7;            // lin%8=b -> batch pinned per XCD
  const int h  = (lin >> 3) & 7;
  const int qt = lin >> 6;

  const int Lb  = 1024 + 128 * b;
  const int off = QOFF[b];
  if (qt * 128 >= Lb) return;        // uniform; lengths are %128==0

  constexpr int KP = 72;             // row stride (bf16): conflict-free class
  constexpr int NC = Nn / 64;        // 32 chunks of 64 keys
  __shared__ ushort Ks[64 * KP];     // [key][d]
  __shared__ ushort Vs[64 * KP];     // [d][sigma(key) within 64]

  const int tid = threadIdx.x;
  const int lane = tid & 63;
  const int w = tid >> 6;            // wave 0..3 -> q-rows [w*32, w*32+32)
  const int c = lane & 15;           // q (B-col) / key-row (A) / d-row (PV A)
  const int g = (lane >> 4) & 3;     // k-chunk selector

  // Q fragments for two 16-row sub-tiles t: rows w*32 + t*16 + c
  short8 qf[2][2];
  int qrow[2];
#pragma unroll
  for (int t = 0; t < 2; ++t) {
    qrow[t] = off + qt * 128 + w * 32 + t * 16 + c;
    const size_t base = (size_t)qrow[t] * Cc + h * Dd + g * 8;
    qf[t][0] = *(const short8*)(qhi + base);
    qf[t][1] = *(const short8*)(qhi + base + 32);
  }

  float l_part[2] = {0.f, 0.f};
  f32x4 accO4[2][4] = {};

  const size_t kbase = (size_t)b * Nn * Cc + h * Dd;
  const size_t vbase = (size_t)h * Dd * (Bb * Nn) + (size_t)b * Nn;

  for (int ch = 0; ch < NC; ++ch) {
    __syncthreads();   // previous chunk's LDS reads complete
    // stage K: 64 keys x 128B (2 short8 per thread)
#pragma unroll
    for (int it = 0; it < 2; ++it) {
      const int i = tid + it * 256;
      const int row = i >> 3, c8 = (i & 7) * 8;
      *(short8*)&Ks[row * KP + c8] =
          *(const short8*)&kbf[kbase + (size_t)(ch * 64 + row) * Cc + c8];
    }
    // stage V: 64 d-rows x 64 keys; sigma^-1 applied to the GLOBAL fetch.
#pragma unroll
    for (int it = 0; it < 2; ++it) {
      const int i = tid + it * 256;
      const int row = i >> 3, c8 = (i & 7) * 8;
      const int kb1 = (c8 & ~31) | (((c8 >> 3) & 3) << 2);
      const size_t gb = vbase + (size_t)row * (Bb * Nn) + ch * 64;
      const u32x2 vlo = *(const u32x2*)&vtb[gb + kb1];
      const u32x2 vhi = *(const u32x2*)&vtb[gb + kb1 + 16];
      u32x4 vv;
      vv[0] = vlo[0]; vv[1] = vlo[1];
      vv[2] = vhi[0]; vv[3] = vhi[1];
      *(short8*)&Vs[row * KP + c8] = __builtin_bit_cast(short8, vv);
    }
    __syncthreads();

    // ---- S^T = K Q^T : one kf read feeds both q-sub-tiles ----
    f32x4 accT4[2][4] = {};
    __builtin_amdgcn_s_setprio(1);
#pragma unroll
    for (int ks2 = 0; ks2 < 2; ++ks2) {
#pragma unroll
      for (int kb = 0; kb < 4; ++kb) {
        const short8 kf = *(const short8*)
            &Ks[(kb * 16 + c) * KP + ks2 * 32 + g * 8];
        accT4[0][kb] = __builtin_amdgcn_mfma_f32_16x16x32_bf16(kf, qf[0][ks2], accT4[0][kb], 0,0,0);
        accT4[1][kb] = __builtin_amdgcn_mfma_f32_16x16x32_bf16(kf, qf[1][ks2], accT4[1][kb], 0,0,0);
      }
    }
    __builtin_amdgcn_s_setprio(0);

    // ---- static softmax: P = exp2(S), pack to bf16 pairs (lane-local) ----
    unsigned int up[2][4][2];
#pragma unroll
    for (int t = 0; t < 2; ++t)
#pragma unroll
      for (int kb = 0; kb < 4; ++kb) {
        const float p0 = __builtin_amdgcn_exp2f(accT4[t][kb][0]);
        const float p1 = __builtin_amdgcn_exp2f(accT4[t][kb][1]);
        const float p2 = __builtin_amdgcn_exp2f(accT4[t][kb][2]);
        const float p3 = __builtin_amdgcn_exp2f(accT4[t][kb][3]);
        l_part[t] += (p0 + p1) + (p2 + p3);
        up[t][kb][0] = pk2(p0, p1);
        up[t][kb][1] = pk2(p2, p3);
      }

    // ---- O^T += V^T P^T ; one vf read feeds both q-sub-tiles ----
#pragma unroll
    for (int ks2 = 0; ks2 < 2; ++ks2) {
      short8 pa[2];
#pragma unroll
      for (int t = 0; t < 2; ++t) {
        u32x4 wv;
        wv.x = up[t][2 * ks2][0];
        wv.y = up[t][2 * ks2][1];
        wv.z = up[t][2 * ks2 + 1][0];
        wv.w = up[t][2 * ks2 + 1][1];
        pa[t] = __builtin_bit_cast(short8, wv);
      }
      __builtin_amdgcn_s_setprio(1);
#pragma unroll
      for (int db = 0; db < 4; ++db) {
        const short8 vf = *(const short8*)
            &Vs[(db * 16 + c) * KP + ks2 * 32 + g * 8];
        accO4[0][db] = __builtin_amdgcn_mfma_f32_16x16x32_bf16(vf, pa[0], accO4[0][db], 0,0,0);
        accO4[1][db] = __builtin_amdgcn_mfma_f32_16x16x32_bf16(vf, pa[1], accO4[1][db], 0,0,0);
      }
      __builtin_amdgcn_s_setprio(0);
    }
  }

  // ---- epilogue: reduce l across the 4 g-groups, normalize, store ----
#pragma unroll
  for (int t = 0; t < 2; ++t) {
    float l = l_part[t];
    l += __shfl_xor(l, 16);
    l += __shfl_xor(l, 32);
    const float inv = 1.f / l;
    const size_t rb = (size_t)qrow[t] * Cc + h * Dd;
#pragma unroll
    for (int db = 0; db < 4; ++db) {
      const int d0 = db * 16 + g * 4;
      ushort4 uh, ul;
#pragma unroll
      for (int e = 0; e < 4; ++e) {
        const float o = accO4[t][db][e] * inv;
        const ushort hb = f2bf(o);
        ((ushort*)&uh)[e] = hb;
        ((ushort*)&ul)[e] = f2bf(o - bf2f(hb));
      }
      *(ushort4*)&ohi[rb + d0] = uh;
      *(ushort4*)&olo[rb + d0] = ul;
    }
  }
}

// ---------------------------------------------------------------------------
extern "C" void kernel_launch(void* const* d_in, const int* in_sizes, int n_in,
                              void* d_out, int out_size, void* d_ws, size_t ws_size,
                              hipStream_t stream)
{
  const float* x     = (const float*)d_in[0];  // (B,N,C)
  const float* q     = (const float*)d_in[1];  // (TQ,C)
  const float* Wq    = (const float*)d_in[2];  // (C,C)
  const float* Wkv   = (const float*)d_in[3];  // (2C,C): rows [0,C)=Wk, [C,2C)=Wv
  const float* Wproj = (const float*)d_in[4];  // (C,C)
  const float* bproj = (const float*)d_in[5];  // (C)

  const int TQ = in_sizes[1] / Cc;   // 11776 (multiple of 128)
  const int BN = in_sizes[0] / Cc;   // 16384

  const size_t szQ = (size_t)TQ * Cc * 2;
  const size_t szX = (size_t)BN * Cc * 2;

  // workspace carve (68 MB total)
  char* p = (char*)d_ws;
  ushort* q_hi  = (ushort*)p;  p += szQ;       // 12 MB
  ushort* k_bf  = (ushort*)p;  p += szX;       // 16 MB
  ushort* v_t   = (ushort*)p;  p += szX;       // 16 MB
  ushort* at_hi = (ushort*)p;  p += szQ;       // 12 MB
  ushort* at_lo = (ushort*)p;                  // 12 MB

  // 1) merged Q + KV projections (880 blocks)
  const int nqb = (TQ / 128) * (Cc / 128);     // 368
  const int nkvb = (BN / 128) * (Cc / 128);    // 512
  proj_qkv_kernel<<<dim3(nqb + nkvb), 256, 0, stream>>>(
      q, Wq, x, Wkv, q_hi, k_bf, v_t, TQ, BN);
  // 2) attention: 64-key chunks, 8 blocks/CU
  attn_mfma14_kernel<<<dim3(64 * 15), 256, 0, stream>>>(
      q_hi, k_bf, v_t, at_hi, at_lo);
  // 3) out = attno @ Wproj^T + bproj, 3-term
  mfma_proj_kernel<<<dim3(Cc/128, TQ/128), 256, 0, stream>>>(
      at_hi, at_lo, Wproj, bproj, (float*)d_out, Cc);
}